// Round 3
// baseline (13620.325 us; speedup 1.0000x reference)
//
#include <hip/hip_runtime.h>

// ---------------------------------------------------------------------------
// Child-Sum TreeLSTM, complete binary tree, level-wise bottom-up, bf16 MFMA.
// Round 3: 32x32x16 MFMA (1 wave = 32 nodes x 32 cols), batched weight loads,
// shared xf = x@Wfx^T plane seeds both forget-gate accumulators, children c
// prefetched before pass 2.
//
// mfma_f32_32x32x16_bf16: A lane: row=l&31, k=(l>>5)*8+e  (16B ds_read)
//                         B lane: col=l&31, k=(l>>5)*8+e = W[col][k] (16B)
//                         D: col=l&31, row=(r&3)+8*(r>>2)+4*(l>>5), r=0..15
// ---------------------------------------------------------------------------

typedef __attribute__((ext_vector_type(8))) short bf16x8;
typedef __attribute__((ext_vector_type(8))) unsigned short us8;
typedef __attribute__((ext_vector_type(16))) float f32x16;

#define LSTR 264   // 256 + 8 bf16 pad (row stride 528 B; uniform bank spread for b128)
#define MT 32      // nodes per block

#define MFMA32(A, B, C) __builtin_amdgcn_mfma_f32_32x32x16_bf16(A, B, C, 0, 0, 0)

__device__ __forceinline__ unsigned short f2b(float f) {
  unsigned int u = __builtin_bit_cast(unsigned int, f);
  u = u + 0x7FFFu + ((u >> 16) & 1u);   // RNE
  return (unsigned short)(u >> 16);
}

__device__ __forceinline__ us8 pack8(float4 a, float4 b) {
  us8 r;
  r[0] = f2b(a.x); r[1] = f2b(a.y); r[2] = f2b(a.z); r[3] = f2b(a.w);
  r[4] = f2b(b.x); r[5] = f2b(b.y); r[6] = f2b(b.z); r[7] = f2b(b.w);
  return r;
}

__device__ __forceinline__ float sigm(float x) { return 1.0f / (1.0f + __expf(-x)); }
__device__ __forceinline__ float tanh_f(float x) { return 2.0f / (1.0f + __expf(-2.0f * x)) - 1.0f; }

__device__ __forceinline__ f32x16 zz16() {
  f32x16 v;
  #pragma unroll
  for (int i = 0; i < 16; ++i) v[i] = 0.f;
  return v;
}

__global__ void pack_w(const float* __restrict__ a,  // Wioux 768x256
                       const float* __restrict__ b,  // Wiouh 768x256
                       const float* __restrict__ c,  // Wfx   256x256
                       const float* __restrict__ d,  // Wfh   256x256
                       unsigned short* __restrict__ out) {
  int i = blockIdx.x * blockDim.x + threadIdx.x;  // 0 .. 524287
  const int A = 768 * 256;
  const int B = A + 768 * 256;
  const int C = B + 256 * 256;
  float v;
  if (i < A)      v = a[i];
  else if (i < B) v = b[i - A];
  else if (i < C) v = c[i - B];
  else            v = d[i - C];
  out[i] = f2b(v);
}

__global__ __launch_bounds__(512, 4) void level_k(
    const float* __restrict__ x_in,
    const unsigned short* __restrict__ Wx,     // bf16 Wioux [768][256]
    const unsigned short* __restrict__ Wh,     // bf16 Wiouh [768][256]
    const unsigned short* __restrict__ Wfxw,   // bf16 Wfx   [256][256]
    const unsigned short* __restrict__ Wfhw,   // bf16 Wfh   [256][256]
    const float* __restrict__ bioux,
    const float* __restrict__ bfx,
    const float* __restrict__ fb,
    float* __restrict__ h_all,                 // d_out + 512
    float* __restrict__ c_all,                 // ws
    float* __restrict__ out0,                  // d_out
    int s, int L, int leaf, int root)
{
  extern __shared__ unsigned short sm[];
  unsigned short* Xs  = sm;                       // [MT][LSTR]
  unsigned short* HSs = sm + MT * LSTR;
  unsigned short* H1s = sm + 2 * MT * LSTR;
  unsigned short* H2s = sm + 3 * MT * LSTR;

  const int tid = threadIdx.x;
  const int nb0 = blockIdx.x * MT;

  // ---- stage MT nodes: x (and h1, h2, h1+h2) as bf16 into LDS ----
  #pragma unroll
  for (int it = 0; it < 2; ++it) {
    const int gl  = tid + it * 512;        // granule id, 0..1023
    const int row = gl >> 5;
    const int col = (gl & 31) * 8;         // element col (8 per granule)
    const int node = nb0 + row;
    float4 x0 = {0,0,0,0}, x1 = {0,0,0,0};
    if (node < L) {
      const float* p = x_in + (size_t)(s + node) * 256 + col;
      x0 = *(const float4*)p; x1 = *(const float4*)(p + 4);
    }
    *(us8*)(Xs + row * LSTR + col) = pack8(x0, x1);
    if (!leaf) {
      float4 a0 = {0,0,0,0}, a1 = {0,0,0,0}, b0 = {0,0,0,0}, b1 = {0,0,0,0};
      if (node < L) {
        const size_t n = (size_t)(s + node);
        const float* p1 = h_all + (2 * n + 1) * 256 + col;
        const float* p2 = h_all + (2 * n + 2) * 256 + col;
        a0 = *(const float4*)p1; a1 = *(const float4*)(p1 + 4);
        b0 = *(const float4*)p2; b1 = *(const float4*)(p2 + 4);
      }
      *(us8*)(H1s + row * LSTR + col) = pack8(a0, a1);
      *(us8*)(H2s + row * LSTR + col) = pack8(b0, b1);
      float4 s0, s1;
      s0.x = a0.x + b0.x; s0.y = a0.y + b0.y; s0.z = a0.z + b0.z; s0.w = a0.w + b0.w;
      s1.x = a1.x + b1.x; s1.y = a1.y + b1.y; s1.z = a1.z + b1.z; s1.w = a1.w + b1.w;
      *(us8*)(HSs + row * LSTR + col) = pack8(s0, s1);
    }
  }
  __syncthreads();

  const int lane = tid & 63;
  const int w    = tid >> 6;          // 0..7 -> col tile
  const int lr   = lane & 31;         // A node-row in tile / B output-col in tile
  const int kh   = lane >> 5;         // k half
  const int koff = kh * 8;
  const int colc = w * 32 + lr;       // this lane's output col

  const unsigned short* wxi  = Wx   + (size_t)colc * 256;  // i rows (o:+65536, u:+131072)
  const unsigned short* whi  = Wh   + (size_t)colc * 256;
  const unsigned short* wfxp = Wfxw + (size_t)colc * 256;
  const unsigned short* wfhp = Wfhw + (size_t)colc * 256;

  f32x16 ai = zz16(), ao = zz16(), au = zz16(), axf = zz16();

  // ---- pass 1: i,o,u (+ xf = x@Wfx^T) over K=256 (x) and K=256 (hsum) ----
  if (!leaf) {
    #pragma unroll 2
    for (int kt = 0; kt < 16; ++kt) {
      const int k0 = kt * 16 + koff;
      bf16x8 bix  = *(const bf16x8*)(wxi + k0);
      bf16x8 box  = *(const bf16x8*)(wxi + 65536 + k0);
      bf16x8 bux  = *(const bf16x8*)(wxi + 131072 + k0);
      bf16x8 bfxv = *(const bf16x8*)(wfxp + k0);
      bf16x8 bih  = *(const bf16x8*)(whi + k0);
      bf16x8 boh  = *(const bf16x8*)(whi + 65536 + k0);
      bf16x8 buh  = *(const bf16x8*)(whi + 131072 + k0);
      bf16x8 ax   = *(const bf16x8*)(Xs  + lr * LSTR + k0);
      bf16x8 ahs  = *(const bf16x8*)(HSs + lr * LSTR + k0);
      ai  = MFMA32(ax,  bix, ai);
      ao  = MFMA32(ax,  box, ao);
      au  = MFMA32(ax,  bux, au);
      axf = MFMA32(ax,  bfxv, axf);
      ai  = MFMA32(ahs, bih, ai);
      ao  = MFMA32(ahs, boh, ao);
      au  = MFMA32(ahs, buh, au);
    }
  } else {
    #pragma unroll 2
    for (int kt = 0; kt < 16; ++kt) {
      const int k0 = kt * 16 + koff;
      bf16x8 bix = *(const bf16x8*)(wxi + k0);
      bf16x8 box = *(const bf16x8*)(wxi + 65536 + k0);
      bf16x8 bux = *(const bf16x8*)(wxi + 131072 + k0);
      bf16x8 ax  = *(const bf16x8*)(Xs + lr * LSTR + k0);
      ai = MFMA32(ax, bix, ai);
      ao = MFMA32(ax, box, ao);
      au = MFMA32(ax, bux, au);
    }
  }

  // ---- i,o,u nonlinearities (frees 3 accumulator planes) ----
  const float bi_ = bioux[colc];
  const float bo_ = bioux[256 + colc];
  const float bu_ = bioux[512 + colc];
  float og[16], iu[16];
  #pragma unroll
  for (int r = 0; r < 16; ++r) {
    og[r] = sigm(ao[r] + bo_);
    iu[r] = sigm(ai[r] + bi_) * tanh_f(au[r] + bu_);
  }

  // ---- prefetch children c (latency hides under pass 2 MFMAs) ----
  float c1v[16], c2v[16];
  #pragma unroll
  for (int r = 0; r < 16; ++r) {
    const int m = (r & 3) + 8 * (r >> 2) + 4 * kh;
    const int node = nb0 + m;
    c1v[r] = 0.f; c2v[r] = 0.f;
    if (!leaf && node < L) {
      const size_t n = (size_t)(s + node);
      c1v[r] = c_all[(2 * n + 1) * 256 + colc];
      c2v[r] = c_all[(2 * n + 2) * 256 + colc];
    }
  }

  // ---- pass 2: f1 = xf + h1@Wfh^T, f2 = xf + h2@Wfh^T (B-frag shared) ----
  f32x16 f1 = axf, f2 = axf;
  if (!leaf) {
    #pragma unroll 4
    for (int kt = 0; kt < 16; ++kt) {
      const int k0 = kt * 16 + koff;
      bf16x8 bfh = *(const bf16x8*)(wfhp + k0);
      bf16x8 a1  = *(const bf16x8*)(H1s + lr * LSTR + k0);
      bf16x8 a2  = *(const bf16x8*)(H2s + lr * LSTR + k0);
      f1 = MFMA32(a1, bfh, f1);
      f2 = MFMA32(a2, bfh, f2);
    }
  }

  // ---- final epilogue ----
  const float bf_ = leaf ? 0.f : (bfx[colc] + fb[colc]);
  #pragma unroll
  for (int r = 0; r < 16; ++r) {
    const int m = (r & 3) + 8 * (r >> 2) + 4 * kh;
    const int node = nb0 + m;
    if (node >= L) continue;
    const size_t n = (size_t)(s + node);
    float cv = iu[r];
    if (!leaf) cv += sigm(f1[r] + bf_) * c1v[r] + sigm(f2[r] + bf_) * c2v[r];
    const float hv = og[r] * tanh_f(cv);
    h_all[n * 256 + colc] = hv;
    c_all[n * 256 + colc] = cv;
    if (root && node == 0) { out0[colc] = hv; out0[256 + colc] = cv; }
  }
}

extern "C" void kernel_launch(void* const* d_in, const int* in_sizes, int n_in,
                              void* d_out, int out_size, void* d_ws, size_t ws_size,
                              hipStream_t stream) {
  const float* inputs = (const float*)d_in[0];
  const float* Wioux  = (const float*)d_in[1];
  const float* bioux  = (const float*)d_in[2];
  const float* Wiouh  = (const float*)d_in[3];
  const float* Wfx    = (const float*)d_in[4];
  const float* bfx    = (const float*)d_in[5];
  const float* Wfh    = (const float*)d_in[6];
  const float* fb     = (const float*)d_in[7];

  const int N = in_sizes[0] / 256;       // 262143
  int depth = 0;
  while (((1 << depth) - 1) < N) ++depth;  // 18

  float* out   = (float*)d_out;
  float* h_all = out + 512;
  float* c_all = (float*)d_ws;
  unsigned short* wb = (unsigned short*)((char*)d_ws + (size_t)N * 256 * 4);

  pack_w<<<2048, 256, 0, stream>>>(Wioux, Wiouh, Wfx, Wfh, wb);

  const unsigned short* pWx  = wb;
  const unsigned short* pWh  = wb + 768 * 256;
  const unsigned short* pWfx = wb + 2 * 768 * 256;
  const unsigned short* pWfh = wb + 2 * 768 * 256 + 256 * 256;

  for (int d = depth - 1; d >= 0; --d) {
    const int L = 1 << d;
    const int s = L - 1;
    const int blocks = (L + MT - 1) / MT;
    const int leaf = (d == depth - 1) ? 1 : 0;
    const size_t shmem = (leaf ? 1 : 4) * (size_t)MT * LSTR * 2;
    level_k<<<blocks, 512, shmem, stream>>>(inputs, pWx, pWh, pWfx, pWfh,
                                            bioux, bfx, fb, h_all, c_all, out,
                                            s, L, leaf, (d == 0) ? 1 : 0);
  }
}

// Round 4
// 1398.508 us; speedup vs baseline: 9.7392x; 9.7392x over previous
//
#include <hip/hip_runtime.h>

// ---------------------------------------------------------------------------
// Child-Sum TreeLSTM, complete binary tree, level-wise bottom-up, bf16 MFMA.
// Round 4: 32x32x16 MFMA, three sequential accumulator passes to keep peak
// live VGPRs ~110 (round 3 spilled catastrophically at a forced 64-reg cap:
// 17.75 GB of scratch writes per dispatch). __launch_bounds__(512,2): the
// second arg empirically acts as blocks/CU -> 16 waves/CU -> 128 VGPR cap.
//
// mfma_f32_32x32x16_bf16: A lane: row=l&31, k=(l>>5)*8+e  (16B ds_read)
//                         B lane: col=l&31, k=(l>>5)*8+e = W[col][k] (16B)
//                         D: col=l&31, row=(r&3)+8*(r>>2)+4*(l>>5), r=0..15
// ---------------------------------------------------------------------------

typedef __attribute__((ext_vector_type(8))) short bf16x8;
typedef __attribute__((ext_vector_type(8))) unsigned short us8;
typedef __attribute__((ext_vector_type(16))) float f32x16;

#define LSTR 264   // 256 + 8 bf16 pad (row stride 528 B)
#define MT 32      // nodes per block

#define MFMA32(A, B, C) __builtin_amdgcn_mfma_f32_32x32x16_bf16(A, B, C, 0, 0, 0)

__device__ __forceinline__ unsigned short f2b(float f) {
  unsigned int u = __builtin_bit_cast(unsigned int, f);
  u = u + 0x7FFFu + ((u >> 16) & 1u);   // RNE
  return (unsigned short)(u >> 16);
}

__device__ __forceinline__ us8 pack8(float4 a, float4 b) {
  us8 r;
  r[0] = f2b(a.x); r[1] = f2b(a.y); r[2] = f2b(a.z); r[3] = f2b(a.w);
  r[4] = f2b(b.x); r[5] = f2b(b.y); r[6] = f2b(b.z); r[7] = f2b(b.w);
  return r;
}

__device__ __forceinline__ float sigm(float x) { return 1.0f / (1.0f + __expf(-x)); }
__device__ __forceinline__ float tanh_f(float x) { return 2.0f / (1.0f + __expf(-2.0f * x)) - 1.0f; }

__device__ __forceinline__ f32x16 zz16() {
  f32x16 v;
  #pragma unroll
  for (int i = 0; i < 16; ++i) v[i] = 0.f;
  return v;
}

__global__ void pack_w(const float* __restrict__ a,  // Wioux 768x256
                       const float* __restrict__ b,  // Wiouh 768x256
                       const float* __restrict__ c,  // Wfx   256x256
                       const float* __restrict__ d,  // Wfh   256x256
                       unsigned short* __restrict__ out) {
  int i = blockIdx.x * blockDim.x + threadIdx.x;  // 0 .. 524287
  const int A = 768 * 256;
  const int B = A + 768 * 256;
  const int C = B + 256 * 256;
  float v;
  if (i < A)      v = a[i];
  else if (i < B) v = b[i - A];
  else if (i < C) v = c[i - B];
  else            v = d[i - C];
  out[i] = f2b(v);
}

__global__ __launch_bounds__(512, 2) void level_k(
    const float* __restrict__ x_in,
    const unsigned short* __restrict__ Wx,     // bf16 Wioux [768][256]
    const unsigned short* __restrict__ Wh,     // bf16 Wiouh [768][256]
    const unsigned short* __restrict__ Wfxw,   // bf16 Wfx   [256][256]
    const unsigned short* __restrict__ Wfhw,   // bf16 Wfh   [256][256]
    const float* __restrict__ bioux,
    const float* __restrict__ bfx,
    const float* __restrict__ fb,
    float* __restrict__ h_all,                 // d_out + 512
    float* __restrict__ c_all,                 // ws
    float* __restrict__ out0,                  // d_out
    int s, int L, int leaf, int root)
{
  extern __shared__ unsigned short sm[];
  unsigned short* Xs  = sm;                       // [MT][LSTR]
  unsigned short* HSs = sm + MT * LSTR;
  unsigned short* H1s = sm + 2 * MT * LSTR;
  unsigned short* H2s = sm + 3 * MT * LSTR;

  const int tid = threadIdx.x;
  const int nb0 = blockIdx.x * MT;

  // ---- stage MT nodes: x (and h1, h2, h1+h2) as bf16 into LDS ----
  #pragma unroll
  for (int it = 0; it < 2; ++it) {
    const int gl  = tid + it * 512;        // granule id, 0..1023
    const int row = gl >> 5;
    const int col = (gl & 31) * 8;         // element col (8 per granule)
    const int node = nb0 + row;
    float4 x0 = {0,0,0,0}, x1 = {0,0,0,0};
    if (node < L) {
      const float* p = x_in + (size_t)(s + node) * 256 + col;
      x0 = *(const float4*)p; x1 = *(const float4*)(p + 4);
    }
    *(us8*)(Xs + row * LSTR + col) = pack8(x0, x1);
    if (!leaf) {
      float4 a0 = {0,0,0,0}, a1 = {0,0,0,0}, b0 = {0,0,0,0}, b1 = {0,0,0,0};
      if (node < L) {
        const size_t n = (size_t)(s + node);
        const float* p1 = h_all + (2 * n + 1) * 256 + col;
        const float* p2 = h_all + (2 * n + 2) * 256 + col;
        a0 = *(const float4*)p1; a1 = *(const float4*)(p1 + 4);
        b0 = *(const float4*)p2; b1 = *(const float4*)(p2 + 4);
      }
      *(us8*)(H1s + row * LSTR + col) = pack8(a0, a1);
      *(us8*)(H2s + row * LSTR + col) = pack8(b0, b1);
      float4 s0, s1;
      s0.x = a0.x + b0.x; s0.y = a0.y + b0.y; s0.z = a0.z + b0.z; s0.w = a0.w + b0.w;
      s1.x = a1.x + b1.x; s1.y = a1.y + b1.y; s1.z = a1.z + b1.z; s1.w = a1.w + b1.w;
      *(us8*)(HSs + row * LSTR + col) = pack8(s0, s1);
    }
  }
  __syncthreads();

  const int lane = tid & 63;
  const int w    = tid >> 6;          // 0..7 -> col tile
  const int lr   = lane & 31;         // A node-row / B output-col within tile
  const int kh   = lane >> 5;         // k half
  const int koff = kh * 8;
  const int colc = w * 32 + lr;       // this lane's output col

  const unsigned short* wxp  = Wx   + (size_t)colc * 256;  // i (o:+65536, u:+131072)
  const unsigned short* whp  = Wh   + (size_t)colc * 256;
  const unsigned short* wfxp = Wfxw + (size_t)colc * 256;
  const unsigned short* wfhp = Wfhw + (size_t)colc * 256;

  const float bi_ = bioux[colc];
  const float bo_ = bioux[256 + colc];
  const float bu_ = bioux[512 + colc];

  float cv[16];

  if (!leaf) {
    const float bf_ = bfx[colc] + fb[colc];

    // ---- P1: xf = x @ Wfx^T (one plane live) ----
    f32x16 axf = zz16();
    for (int kt = 0; kt < 16; ++kt) {
      const int k0 = kt * 16 + koff;
      bf16x8 bfxv = *(const bf16x8*)(wfxp + k0);
      bf16x8 ax   = *(const bf16x8*)(Xs + lr * LSTR + k0);
      axf = MFMA32(ax, bfxv, axf);
    }
    float xf[16];
    #pragma unroll
    for (int r = 0; r < 16; ++r) xf[r] = axf[r] + bf_;

    // ---- prefetch children c (hides under P2 MFMAs) ----
    float c1v[16], c2v[16];
    #pragma unroll
    for (int r = 0; r < 16; ++r) {
      const int m = (r & 3) + 8 * (r >> 2) + 4 * kh;
      const int node = nb0 + m;
      c1v[r] = 0.f; c2v[r] = 0.f;
      if (node < L) {
        const size_t n = (size_t)(s + node);
        c1v[r] = c_all[(2 * n + 1) * 256 + colc];
        c2v[r] = c_all[(2 * n + 2) * 256 + colc];
      }
    }

    // ---- P2: f1 = h1@Wfh^T, f2 = h2@Wfh^T (B-frag shared) ----
    f32x16 f1 = zz16(), f2 = zz16();
    for (int kt = 0; kt < 16; ++kt) {
      const int k0 = kt * 16 + koff;
      bf16x8 bfh = *(const bf16x8*)(wfhp + k0);
      bf16x8 a1  = *(const bf16x8*)(H1s + lr * LSTR + k0);
      bf16x8 a2  = *(const bf16x8*)(H2s + lr * LSTR + k0);
      f1 = MFMA32(a1, bfh, f1);
      f2 = MFMA32(a2, bfh, f2);
    }
    #pragma unroll
    for (int r = 0; r < 16; ++r)
      cv[r] = sigm(xf[r] + f1[r]) * c1v[r] + sigm(xf[r] + f2[r]) * c2v[r];

    // ---- P3: i,o,u = x@Wioux^T + hsum@Wiouh^T (three planes live) ----
    f32x16 ai = zz16(), ao = zz16(), au = zz16();
    for (int kt = 0; kt < 16; ++kt) {
      const int k0 = kt * 16 + koff;
      bf16x8 bix = *(const bf16x8*)(wxp + k0);
      bf16x8 box = *(const bf16x8*)(wxp + 65536 + k0);
      bf16x8 bux = *(const bf16x8*)(wxp + 131072 + k0);
      bf16x8 bih = *(const bf16x8*)(whp + k0);
      bf16x8 boh = *(const bf16x8*)(whp + 65536 + k0);
      bf16x8 buh = *(const bf16x8*)(whp + 131072 + k0);
      bf16x8 ax  = *(const bf16x8*)(Xs  + lr * LSTR + k0);
      bf16x8 ahs = *(const bf16x8*)(HSs + lr * LSTR + k0);
      ai = MFMA32(ax,  bix, ai);
      ao = MFMA32(ax,  box, ao);
      au = MFMA32(ax,  bux, au);
      ai = MFMA32(ahs, bih, ai);
      ao = MFMA32(ahs, boh, ao);
      au = MFMA32(ahs, buh, au);
    }

    // ---- epilogue ----
    #pragma unroll
    for (int r = 0; r < 16; ++r) {
      const int m = (r & 3) + 8 * (r >> 2) + 4 * kh;
      const int node = nb0 + m;
      if (node >= L) continue;
      const size_t n = (size_t)(s + node);
      float c_ = cv[r] + sigm(ai[r] + bi_) * tanh_f(au[r] + bu_);
      const float hv = sigm(ao[r] + bo_) * tanh_f(c_);
      h_all[n * 256 + colc] = hv;
      c_all[n * 256 + colc] = c_;
      if (root && node == 0) { out0[colc] = hv; out0[256 + colc] = c_; }
    }
  } else {
    // ---- leaves: i,o,u from x only ----
    f32x16 ai = zz16(), ao = zz16(), au = zz16();
    for (int kt = 0; kt < 16; ++kt) {
      const int k0 = kt * 16 + koff;
      bf16x8 bix = *(const bf16x8*)(wxp + k0);
      bf16x8 box = *(const bf16x8*)(wxp + 65536 + k0);
      bf16x8 bux = *(const bf16x8*)(wxp + 131072 + k0);
      bf16x8 ax  = *(const bf16x8*)(Xs + lr * LSTR + k0);
      ai = MFMA32(ax, bix, ai);
      ao = MFMA32(ax, box, ao);
      au = MFMA32(ax, bux, au);
    }
    #pragma unroll
    for (int r = 0; r < 16; ++r) {
      const int m = (r & 3) + 8 * (r >> 2) + 4 * kh;
      const int node = nb0 + m;
      if (node >= L) continue;
      const size_t n = (size_t)(s + node);
      const float c_ = sigm(ai[r] + bi_) * tanh_f(au[r] + bu_);
      const float hv = sigm(ao[r] + bo_) * tanh_f(c_);
      h_all[n * 256 + colc] = hv;
      c_all[n * 256 + colc] = c_;
    }
  }
}

extern "C" void kernel_launch(void* const* d_in, const int* in_sizes, int n_in,
                              void* d_out, int out_size, void* d_ws, size_t ws_size,
                              hipStream_t stream) {
  const float* inputs = (const float*)d_in[0];
  const float* Wioux  = (const float*)d_in[1];
  const float* bioux  = (const float*)d_in[2];
  const float* Wiouh  = (const float*)d_in[3];
  const float* Wfx    = (const float*)d_in[4];
  const float* bfx    = (const float*)d_in[5];
  const float* Wfh    = (const float*)d_in[6];
  const float* fb     = (const float*)d_in[7];

  const int N = in_sizes[0] / 256;       // 262143
  int depth = 0;
  while (((1 << depth) - 1) < N) ++depth;  // 18

  float* out   = (float*)d_out;
  float* h_all = out + 512;
  float* c_all = (float*)d_ws;
  unsigned short* wb = (unsigned short*)((char*)d_ws + (size_t)N * 256 * 4);

  pack_w<<<2048, 256, 0, stream>>>(Wioux, Wiouh, Wfx, Wfh, wb);

  const unsigned short* pWx  = wb;
  const unsigned short* pWh  = wb + 768 * 256;
  const unsigned short* pWfx = wb + 2 * 768 * 256;
  const unsigned short* pWfh = wb + 2 * 768 * 256 + 256 * 256;

  for (int d = depth - 1; d >= 0; --d) {
    const int L = 1 << d;
    const int s = L - 1;
    const int blocks = (L + MT - 1) / MT;
    const int leaf = (d == depth - 1) ? 1 : 0;
    const size_t shmem = (leaf ? 1 : 4) * (size_t)MT * LSTR * 2;
    level_k<<<blocks, 512, shmem, stream>>>(inputs, pWx, pWh, pWfx, pWfh,
                                            bioux, bfx, fb, h_all, c_all, out,
                                            s, L, leaf, (d == 0) ? 1 : 0);
  }
}